// Round 2
// baseline (259.179 us; speedup 1.0000x reference)
//
#include <hip/hip_runtime.h>

// Patch_Embed_Center_Rotate: x (256,3,224,224) f32, P=16, grid 14x14.
// out = x everywhere, except patches with grid col j in [5,9] AND grid row
// k in [5,9], which are transposed within the 16x16 patch:
//   out[b,c, k*16+a3, j*16+a4] = x[b,c, k*16+a4, j*16+a3]
//
// One wave per patch: 64 lanes x float4 = 256 floats = one 16x16 patch.
// Lane (r = lane>>2, c4 = lane&3) covers row r, cols 4*c4..4*c4+3.
// Load/store touch 16 fully-covered 64B lines per instruction -> perfect
// HBM efficiency both directions. Center patches transpose via a per-wave
// LDS region (stride 20 floats: float4 writes stay 16B-aligned; scalar
// read-back is exactly 2-way bank aliased = free). `center` is
// wave-uniform -> no divergence. __syncthreads() is block-uniform.
//
// 768 (b*c) * 196 patches = 150528 waves = 37632 blocks * 4 waves. Exact.

__global__ __launch_bounds__(256) void patch_rotate_kernel(
    const float* __restrict__ x, float* __restrict__ out) {
  __shared__ float lds[4 * 16 * 20];  // 4 waves * 16 rows * stride 20

  int tid    = threadIdx.x;
  int lane   = tid & 63;
  int wavein = tid >> 6;
  int w  = blockIdx.x * 4 + wavein;   // global patch id
  int bc = w / 196;                   // fused (b,c)
  int t  = w - bc * 196;
  int k  = t / 14;                    // grid row
  int j  = t - k * 14;                // grid col
  int r  = lane >> 2;                 // patch row 0..15
  int c4 = lane & 3;                  // float4 col 0..3

  int off = bc * 50176 + (k * 16 + r) * 224 + j * 16 + c4 * 4;
  float4 v = *(const float4*)(x + off);

  bool center = (j >= 5) & (j <= 9) & (k >= 5) & (k <= 9);  // wave-uniform
  float* my = lds + wavein * 320;

  if (center) {
    *(float4*)(my + r * 20 + c4 * 4) = v;   // row-major into LDS
  }
  __syncthreads();                           // uniform across block
  if (center) {
    int c0 = c4 * 4;
    v.x = my[(c0 + 0) * 20 + r];             // v.m = x[c0+m][r]
    v.y = my[(c0 + 1) * 20 + r];
    v.z = my[(c0 + 2) * 20 + r];
    v.w = my[(c0 + 3) * 20 + r];
  }
  *(float4*)(out + off) = v;
}

extern "C" void kernel_launch(void* const* d_in, const int* in_sizes, int n_in,
                              void* d_out, int out_size, void* d_ws, size_t ws_size,
                              hipStream_t stream) {
  const float* x = (const float*)d_in[0];
  float* out = (float*)d_out;
  // 256*3 images * 196 patches = 150528 waves; 4 waves per 256-thread block.
  int blocks = 150528 / 4;  // 37632
  patch_rotate_kernel<<<blocks, 256, 0, stream>>>(x, out);
}